// Round 23
// baseline (793.804 us; speedup 1.0000x reference)
//
#include <hip/hip_runtime.h>

typedef unsigned int u32;
typedef unsigned short u16;
typedef _Float16 f16;
typedef __attribute__((ext_vector_type(8))) _Float16 f16x8;
typedef __attribute__((ext_vector_type(4))) float f32x4;
typedef __attribute__((ext_vector_type(4))) u16 u16x4;

#define L_ 128
#define N_ 512
#define M_ 256
#define TK_ 4
#define H_ 8
#define R_ (L_*N_)
#define FF_ 1024
// LDS frag-buffer strides (u16): MUST stay multiples of 8 u16 (16B) for b128 alignment
#define FS 1024
#define HS 512

__device__ __forceinline__ u16 f2h(float v){ f16 h=(f16)v; return __builtin_bit_cast(u16,h); }
__device__ __forceinline__ float h2f(u16 b){ return (float)__builtin_bit_cast(f16,b); }
__device__ __forceinline__ f32x4 mfmah(f16x8 a, f16x8 b, f32x4 c){
  return __builtin_amdgcn_mfma_f32_16x16x32_f16(a,b,c,0,0,0);
}
// sigmoid-form gelu: x * sigmoid(1.702x)
__device__ __forceinline__ float gelu_f(float x){
  float e = __expf(-1.702f*x);
  float r = __builtin_amdgcn_rcpf(e + 1.f);
  return x*r;
}

// Weight frag-major packing in GLOBAL (1024-stride, 512-half):
//   dst[(cg*(K/64)+k64)*1024 + st*512 + g*128 + lr*8 + e] = W[cg*16+lr][k64*64+st*32+g*8+e]

// ---------------- prep ----------------
__global__ void k_bias(float* __restrict__ bias){
  int j = blockIdx.x, l = threadIdx.x;
  int t = l>>1;
  float base = expf(-0.14391156831212757f * (float)t); // ln(10000)/64
  float ang = (float)j * base;
  bias[j*M_ + l] = (l&1) ? cosf(ang) : sinf(ang);
}

__global__ void k_pack(const float* __restrict__ src, u16* __restrict__ dst, int K){
  int b = blockIdx.x; int nk = K>>6; int cg = b/nk, k64 = b%nk;
  int t = threadIdx.x;
  int st = t>>6, g = (t>>4)&3, lr = t&15;
  const float* sp = src + (cg*16+lr)*K + k64*64 + st*32 + g*8;
  f16x8 hv;
  #pragma unroll
  for (int e=0;e<8;e++) hv[e] = (f16)sp[e];
  *(f16x8*)(dst + b*1024 + t*8) = hv;
}

__global__ void k_pack_qkv(const float* __restrict__ w, u16* __restrict__ dst){
  int b = blockIdx.x;              // a*192 + grp*4 + k64
  int a = b/192; int rmn = b%192; int grp = rmn>>2, k64 = rmn&3;
  int hd = grp/6, cidx = grp%6;
  int t = threadIdx.x;
  int st = t>>6, g = (t>>4)&3, lr = t&15;
  int cl = cidx*16 + lr;           // 0..95
  int x = cl>>5, d = cl&31;
  const float* sp = w + (((a*3+x)*H_+hd)*32 + d)*M_ + k64*64 + st*32 + g*8;
  f16x8 hv;
  #pragma unroll
  for (int e=0;e<8;e++) hv[e] = (f16)sp[e];
  *(f16x8*)(dst + b*1024 + t*8) = hv;
}

// A-staging (f16 src): 64 rows -> frag LDS. Coalesced 64B/thread.
__device__ __forceinline__ void stageA16(const u16* __restrict__ src, u16* __restrict__ Abuf,
                                         int rowbase, int tid){
  int row = tid>>3, skh = tid&7;
  int k64 = skh>>1, st = skh&1;
  int rg = row>>4, lr = row&15;
  const u16* sp = src + (rowbase+row)*M_ + k64*64 + st*32;
  u16* dp = Abuf + (k64*4+rg)*FS + st*HS + lr*8;
  #pragma unroll
  for (int gg=0;gg<4;gg++)
    *(uint4*)(dp + gg*128) = *(const uint4*)(sp + gg*8);
}

// ---------------- k_init: z = x @ weight^T + bias; s16=f16(z), P1=f16(LN(z)) ----------------
__global__ __launch_bounds__(512) void k_init(const float* __restrict__ X, const u16* __restrict__ Wf,
    const float* __restrict__ bias, const float* __restrict__ lg, const float* __restrict__ lb,
    u16* __restrict__ s16, u16* __restrict__ P1){
  __shared__ __align__(16) u16 Abuf[16*FS];
  __shared__ float zs[8][64][2];
  int tid = threadIdx.x;
  int wx = tid>>6, lane = tid&63;
  int g = lane>>4, lr = lane&15;
  int lo = g*128 + lr*8;
  int rowbase = blockIdx.x*64;
  { // stage A (f32 -> f16 frag-pack)
    int row = tid>>3, skh = tid&7;
    int k64 = skh>>1, st = skh&1;
    int rg = row>>4, slr = row&15;
    const float* sp = X + (rowbase+row)*M_ + k64*64 + st*32;
    u16* dp = Abuf + (k64*4+rg)*FS + st*HS + slr*8;
    #pragma unroll
    for (int gg=0;gg<4;gg++){
      f16x8 hv;
      #pragma unroll
      for (int e=0;e<8;e++) hv[e] = (f16)sp[gg*8+e];
      *(f16x8*)(dp + gg*128) = hv;
    }
  }
  __syncthreads();
  f32x4 acc[4][2];
  #pragma unroll
  for (int i=0;i<4;i++){ acc[i][0]=0.f; acc[i][1]=0.f; }
  __builtin_amdgcn_s_setprio(1);
  #pragma unroll
  for (int k64=0;k64<4;k64++)
    #pragma unroll
    for (int st=0;st<2;st++){
      f16x8 a[4], b[2];
      #pragma unroll
      for (int i=0;i<4;i++) a[i] = *(const f16x8*)(Abuf + (k64*4 + i)*FS + st*HS + lo);
      #pragma unroll
      for (int j=0;j<2;j++) b[j] = *(const f16x8*)(Wf + ((wx*2+j)*4 + k64)*1024 + st*512 + lo);
      #pragma unroll
      for (int i=0;i<4;i++)
        #pragma unroll
        for (int j=0;j<2;j++) acc[i][j] = mfmah(a[i], b[j], acc[i][j]);
    }
  __builtin_amdgcn_s_setprio(0);
  // epilogue: +bias -> s16; LN -> P1
  #pragma unroll
  for (int i=0;i<4;i++)
    #pragma unroll
    for (int j=0;j<2;j++)
      #pragma unroll
      for (int r=0;r<4;r++){
        int row = rowbase + i*16 + g*4 + r;
        int col = wx*32 + j*16 + lr;
        acc[i][j][r] += bias[(row & (N_-1))*M_ + col];
        s16[row*M_ + col] = f2h(acc[i][j][r]);
      }
  #pragma unroll
  for (int i=0;i<4;i++)
    #pragma unroll
    for (int r=0;r<4;r++){
      float ps = 0.f, qs = 0.f;
      #pragma unroll
      for (int j=0;j<2;j++){ float t = acc[i][j][r]; ps += t; qs += t*t; }
      ps += __shfl_xor(ps,1); qs += __shfl_xor(qs,1);
      ps += __shfl_xor(ps,2); qs += __shfl_xor(qs,2);
      ps += __shfl_xor(ps,4); qs += __shfl_xor(qs,4);
      ps += __shfl_xor(ps,8); qs += __shfl_xor(qs,8);
      if (lr == 0){
        int rowl = i*16 + g*4 + r;
        zs[wx][rowl][0] = ps;
        zs[wx][rowl][1] = qs;
      }
    }
  __syncthreads();
  #pragma unroll
  for (int i=0;i<4;i++)
    #pragma unroll
    for (int r=0;r<4;r++){
      int rowl = i*16 + g*4 + r;
      float sum=0.f, sq=0.f;
      #pragma unroll
      for (int q=0;q<8;q++){ sum += zs[q][rowl][0]; sq += zs[q][rowl][1]; }
      float mean = sum*(1.f/M_);
      float var  = sq*(1.f/M_) - mean*mean;
      float rstd = rsqrtf(var + 1e-5f);
      int row = rowbase + rowl;
      #pragma unroll
      for (int j=0;j<2;j++){
        int col = wx*32 + j*16 + lr;
        P1[row*M_ + col] = f2h((acc[i][j][r]-mean)*rstd*lg[col] + lb[col]);
      }
    }
}

// ---------------- QKV GEMM + fused rsa -> imv(f16), 2-pass (QK then V) ----------------
__global__ __launch_bounds__(512) void k_qkv(const u16* __restrict__ P1, const u16* __restrict__ Wq,
    u16* __restrict__ imv){
  __shared__ __align__(16) u16 Abuf[16*FS];
  int tid = threadIdx.x;
  int hd = tid>>6, lane = tid&63;
  int g = lane>>4, lr = lane&15;
  int lo = g*128 + lr*8;
  int rowbase = blockIdx.x*64;
  stageA16(P1, Abuf, rowbase, tid);
  __syncthreads();
  const u16* Wb = Wq + hd*6*4096;
  const float isd = 0.17677669529663687f; // 1/sqrt(32)
  // ---- pass 1: q,k (c=0..3) ----
  float rsa[4][4];
  {
    f32x4 aqk[4][4];
    #pragma unroll
    for (int i=0;i<4;i++)
      #pragma unroll
      for (int c=0;c<4;c++) aqk[i][c] = 0.f;
    __builtin_amdgcn_s_setprio(1);
    #pragma unroll
    for (int k64=0;k64<4;k64++)
      #pragma unroll
      for (int st=0;st<2;st++){
        f16x8 a[4];
        #pragma unroll
        for (int i=0;i<4;i++) a[i] = *(const f16x8*)(Abuf + (k64*4 + i)*FS + st*HS + lo);
        #pragma unroll
        for (int c=0;c<4;c++){
          f16x8 b = *(const f16x8*)(Wb + (c*4 + k64)*1024 + st*512 + lo);
          #pragma unroll
          for (int i=0;i<4;i++) aqk[i][c] = mfmah(a[i], b, aqk[i][c]);
        }
      }
    __builtin_amdgcn_s_setprio(0);
    #pragma unroll
    for (int i=0;i<4;i++){
      f32x4 p = aqk[i][0]*aqk[i][2] + aqk[i][1]*aqk[i][3];
      #pragma unroll
      for (int r=0;r<4;r++){
        float v = p[r];
        v += __shfl_xor(v,1); v += __shfl_xor(v,2);
        v += __shfl_xor(v,4); v += __shfl_xor(v,8);
        rsa[i][r] = v * isd;
      }
    }
  }
  // ---- pass 2: v (c=4,5) ----
  f32x4 av[4][2];
  #pragma unroll
  for (int i=0;i<4;i++){ av[i][0]=0.f; av[i][1]=0.f; }
  __builtin_amdgcn_s_setprio(1);
  #pragma unroll
  for (int k64=0;k64<4;k64++)
    #pragma unroll
    for (int st=0;st<2;st++){
      f16x8 a[4];
      #pragma unroll
      for (int i=0;i<4;i++) a[i] = *(const f16x8*)(Abuf + (k64*4 + i)*FS + st*HS + lo);
      #pragma unroll
      for (int c=0;c<2;c++){
        f16x8 b = *(const f16x8*)(Wb + ((4+c)*4 + k64)*1024 + st*512 + lo);
        #pragma unroll
        for (int i=0;i<4;i++) av[i][c] = mfmah(a[i], b, av[i][c]);
      }
    }
  __builtin_amdgcn_s_setprio(0);
  #pragma unroll
  for (int i=0;i<4;i++)
    #pragma unroll
    for (int r=0;r<4;r++){
      int row = rowbase + i*16 + g*4 + r;
      imv[row*M_ + hd*32 + lr]      = f2h(rsa[i][r]*av[i][0][r]);
      imv[row*M_ + hd*32 + 16 + lr] = f2h(rsa[i][r]*av[i][1][r]);
    }
}

// ---------------- cumsum over j: u32-pair vectorized; grid (L_*2), block (64 mpair x 4 jc) ----------------
__global__ __launch_bounds__(256) void k_scan(const u16* __restrict__ imv, u16* __restrict__ P1){
  __shared__ float tot[4][64][2];
  const u32* s32 = (const u32*)imv;
  u32* d32 = (u32*)P1;
  int bi = blockIdx.x;
  int i = bi>>1, mc = bi&1;
  int tid = threadIdx.x;
  int ml = tid&63, jc = tid>>6;
  int base = i*(N_*M_/2) + jc*128*(M_/2) + mc*64 + ml;   // u32 units
  float a0 = 0.f, a1 = 0.f;
  for (int jb=0;jb<128;jb+=8){
    u32 t[8];
    #pragma unroll
    for (int u=0;u<8;u++) t[u] = s32[base + (jb+u)*(M_/2)];
    #pragma unroll
    for (int u=0;u<8;u++){ a0 += h2f((u16)(t[u]&0xffff)); a1 += h2f((u16)(t[u]>>16)); }
  }
  tot[jc][ml][0] = a0; tot[jc][ml][1] = a1;
  __syncthreads();
  float p0 = 0.f, p1 = 0.f;
  #pragma unroll
  for (int q=0;q<3;q++) if (q<jc){ p0 += tot[q][ml][0]; p1 += tot[q][ml][1]; }
  a0 = p0; a1 = p1;
  for (int jb=0;jb<128;jb+=8){
    u32 t[8];
    #pragma unroll
    for (int u=0;u<8;u++) t[u] = s32[base + (jb+u)*(M_/2)];
    #pragma unroll
    for (int u=0;u<8;u++){
      a0 += h2f((u16)(t[u]&0xffff));
      a1 += h2f((u16)(t[u]>>16));
      d32[base + (jb+u)*(M_/2)] = (u32)f2h(a0) | ((u32)f2h(a1)<<16);
    }
  }
}

// ---------------- Wo GEMM + s_old(f16) + LN + residual -> P1(f16, in-place) ----------------
__global__ __launch_bounds__(512) void k_wo(u16* __restrict__ P1, const u16* __restrict__ Wf,
    const u16* __restrict__ s16, const float* __restrict__ lg, const float* __restrict__ lb){
  __shared__ __align__(16) u16 Abuf[16*FS];
  __shared__ float zs[8][64][2];
  int tid = threadIdx.x;
  int wx = tid>>6, lane = tid&63;
  int g = lane>>4, lr = lane&15;
  int lo = g*128 + lr*8;
  int rowbase = blockIdx.x*64;
  stageA16(P1, Abuf, rowbase, tid);
  __syncthreads();
  f32x4 acc[4][2];
  #pragma unroll
  for (int i=0;i<4;i++){ acc[i][0]=0.f; acc[i][1]=0.f; }
  __builtin_amdgcn_s_setprio(1);
  #pragma unroll
  for (int k64=0;k64<4;k64++)
    #pragma unroll
    for (int st=0;st<2;st++){
      f16x8 a[4], b[2];
      #pragma unroll
      for (int i=0;i<4;i++) a[i] = *(const f16x8*)(Abuf + (k64*4 + i)*FS + st*HS + lo);
      #pragma unroll
      for (int j=0;j<2;j++) b[j] = *(const f16x8*)(Wf + ((wx*2+j)*4 + k64)*1024 + st*512 + lo);
      #pragma unroll
      for (int i=0;i<4;i++)
        #pragma unroll
        for (int j=0;j<2;j++) acc[i][j] = mfmah(a[i], b[j], acc[i][j]);
    }
  __builtin_amdgcn_s_setprio(0);
  #pragma unroll
  for (int i=0;i<4;i++)
    #pragma unroll
    for (int j=0;j<2;j++)
      #pragma unroll
      for (int r=0;r<4;r++){
        int row = rowbase + i*16 + g*4 + r;
        int col = wx*32 + j*16 + lr;
        acc[i][j][r] += h2f(s16[row*M_ + col]);
      }
  #pragma unroll
  for (int i=0;i<4;i++)
    #pragma unroll
    for (int r=0;r<4;r++){
      float ps = 0.f, qs = 0.f;
      #pragma unroll
      for (int j=0;j<2;j++){ float t = acc[i][j][r]; ps += t; qs += t*t; }
      ps += __shfl_xor(ps,1); qs += __shfl_xor(qs,1);
      ps += __shfl_xor(ps,2); qs += __shfl_xor(qs,2);
      ps += __shfl_xor(ps,4); qs += __shfl_xor(qs,4);
      ps += __shfl_xor(ps,8); qs += __shfl_xor(qs,8);
      if (lr == 0){
        int rowl = i*16 + g*4 + r;
        zs[wx][rowl][0] = ps;
        zs[wx][rowl][1] = qs;
      }
    }
  __syncthreads();
  #pragma unroll
  for (int i=0;i<4;i++)
    #pragma unroll
    for (int r=0;r<4;r++){
      int rowl = i*16 + g*4 + r;
      float sum=0.f, sq=0.f;
      #pragma unroll
      for (int q=0;q<8;q++){ sum += zs[q][rowl][0]; sq += zs[q][rowl][1]; }
      float mean = sum*(1.f/M_);
      float var  = sq*(1.f/M_) - mean*mean;
      float rstd = rsqrtf(var + 1e-5f);
      int row = rowbase + rowl;
      #pragma unroll
      for (int j=0;j<2;j++){
        int col = wx*32 + j*16 + lr;
        float zv = acc[i][j][r];
        P1[row*M_ + col] = f2h((zv-mean)*rstd*lg[col] + lb[col] + zv);
      }
    }
}

// ---------------- fused MLP + LN (R20 config + T5 setprio) ----------------
// LAST=0: z -> s16(f16), LN(z) -> P1.  LAST=1: z -> out(f32) only.
template<int LAST>
__global__ __launch_bounds__(512) void k_fc(u16* __restrict__ P1,
    const u16* __restrict__ W1f, const float* __restrict__ b1,
    const u16* __restrict__ W2f, const float* __restrict__ b2,
    const float* __restrict__ lg, const float* __restrict__ lb,
    u16* __restrict__ s16, float* __restrict__ out){
  __shared__ __align__(16) u16 Abuf[16*FS];
  __shared__ __align__(16) u16 Hbuf[2][64*128];  // 32KB
  __shared__ float zs[8][64][2];                 // 4KB
  int tid = threadIdx.x;
  int wx = tid>>6, lane = tid&63;
  int g = lane>>4, lr = lane&15;
  int lo = g*128 + lr*8;
  int rowbase = blockIdx.x*64;
  stageA16(P1, Abuf, rowbase, tid);
  __syncthreads();
  f32x4 acc2[4][2];
  #pragma unroll
  for (int i=0;i<4;i++){ acc2[i][0]=0.f; acc2[i][1]=0.f; }
  for (int c=0;c<8;c++){
    u16* Hb = Hbuf[c&1];
    // ---- FC1^T: this wave's 16 fcols = c*128 + wx*16; K=256 ----
    f32x4 acc1[4];
    #pragma unroll
    for (int j=0;j<4;j++) acc1[j] = 0.f;
    __builtin_amdgcn_s_setprio(1);
    #pragma unroll
    for (int k64=0;k64<4;k64++)
      #pragma unroll
      for (int st=0;st<2;st++){
        f16x8 aw = *(const f16x8*)(W1f + ((c*8 + wx)*4 + k64)*1024 + st*512 + lo);
        #pragma unroll
        for (int j=0;j<4;j++){
          f16x8 bs = *(const f16x8*)(Abuf + (k64*4 + j)*FS + st*HS + lo);
          acc1[j] = mfmah(aw, bs, acc1[j]);
        }
      }
    __builtin_amdgcn_s_setprio(0);
    // ---- gelu -> Hb (A-frag layout, XOR-swizzled) ----
    {
      int fl = wx*16 + g*4;            // fcol local 0..127 (+r)
      int kc = fl>>6, kloc = fl&63;
      float4 b1v = *(const float4*)(b1 + c*128 + fl);
      float bb[4] = {b1v.x, b1v.y, b1v.z, b1v.w};
      #pragma unroll
      for (int j=0;j<4;j++){
        int row = j*16 + lr;
        u16x4 hv;
        #pragma unroll
        for (int r=0;r<4;r++)
          hv[r] = f2h(gelu_f(acc1[j][r] + bb[r]));
        int phys = ((kloc>>3) ^ row) & 7;
        *(u16x4*)(Hb + row*128 + kc*64 + phys*8 + (kloc&7)) = hv;
      }
    }
    __syncthreads();   // only barrier per chunk: H(c) visible; prev readers used other buffer
    // ---- FC2 partial: k in [c*128,+128); out cols wx*32..+32 ----
    __builtin_amdgcn_s_setprio(1);
    #pragma unroll
    for (int kcl=0;kcl<2;kcl++)
      #pragma unroll
      for (int st=0;st<2;st++){
        f16x8 ah[4], bb2[2];
        #pragma unroll
        for (int j=0;j<2;j++)
          bb2[j] = *(const f16x8*)(W2f + ((wx*2+j)*16 + c*2 + kcl)*1024 + st*512 + lo);
        #pragma unroll
        for (int i=0;i<4;i++){
          int hrow = i*16 + lr;
          int phys = (((st<<2)|g) ^ hrow) & 7;
          ah[i] = *(const f16x8*)(Hb + hrow*128 + kcl*64 + phys*8);
        }
        #pragma unroll
        for (int i=0;i<4;i++)
          #pragma unroll
          for (int j=0;j<2;j++) acc2[i][j] = mfmah(ah[i], bb2[j], acc2[i][j]);
      }
    __builtin_amdgcn_s_setprio(0);
  }
  // ---- epilogue ----
  #pragma unroll
  for (int i=0;i<4;i++)
    #pragma unroll
    for (int j=0;j<2;j++)
      #pragma unroll
      for (int r=0;r<4;r++){
        int row = rowbase + i*16 + g*4 + r;
        int col = wx*32 + j*16 + lr;
        acc2[i][j][r] += b2[col];
        if (LAST) out[row*M_ + col] = acc2[i][j][r];
        else      s16[row*M_ + col] = f2h(acc2[i][j][r]);
      }
  if (!LAST){
    #pragma unroll
    for (int i=0;i<4;i++)
      #pragma unroll
      for (int r=0;r<4;r++){
        float ps = 0.f, qs = 0.f;
        #pragma unroll
        for (int j=0;j<2;j++){ float t = acc2[i][j][r]; ps += t; qs += t*t; }
        ps += __shfl_xor(ps,1); qs += __shfl_xor(qs,1);
        ps += __shfl_xor(ps,2); qs += __shfl_xor(qs,2);
        ps += __shfl_xor(ps,4); qs += __shfl_xor(qs,4);
        ps += __shfl_xor(ps,8); qs += __shfl_xor(qs,8);
        if (lr == 0){
          int rowl = i*16 + g*4 + r;
          zs[wx][rowl][0] = ps;
          zs[wx][rowl][1] = qs;
        }
      }
    __syncthreads();
    #pragma unroll
    for (int i=0;i<4;i++)
      #pragma unroll
      for (int r=0;r<4;r++){
        int rowl = i*16 + g*4 + r;
        float sum=0.f, sq=0.f;
        #pragma unroll
        for (int q=0;q<8;q++){ sum += zs[q][rowl][0]; sq += zs[q][rowl][1]; }
        float mean = sum*(1.f/M_);
        float var  = sq*(1.f/M_) - mean*mean;
        float rstd = rsqrtf(var + 1e-5f);
        int row = rowbase + rowl;
        #pragma unroll
        for (int j=0;j<2;j++){
          int col = wx*32 + j*16 + lr;
          P1[row*M_ + col] = f2h((acc2[i][j][r]-mean)*rstd*lg[col] + lb[col]);
        }
      }
  }
}

extern "C" void kernel_launch(void* const* d_in, const int* in_sizes, int n_in,
                              void* d_out, int out_size, void* d_ws, size_t ws_size,
                              hipStream_t stream){
  const float* x      = (const float*)d_in[0];
  const float* weight = (const float*)d_in[1];
  const float* wqkv   = (const float*)d_in[2];
  const float* wo     = (const float*)d_in[3];
  const float* ln_g   = (const float*)d_in[4];
  const float* ln_b   = (const float*)d_in[5];
  const float* lnz_g  = (const float*)d_in[6];
  const float* lnz_b  = (const float*)d_in[7];
  const float* fc1_w  = (const float*)d_in[8];
  const float* fc1_b  = (const float*)d_in[9];
  const float* fc2_w  = (const float*)d_in[10];
  const float* fc2_b  = (const float*)d_in[11];
  float* out = (float*)d_out;
  char* ws = (char*)d_ws;
  size_t off = 0;
  u16* wqkvf = (u16*)(ws + off); off += 1572864;   // 4*192 frags
  u16* wof   = (u16*)(ws + off); off += 524288;
  u16* fc1f  = (u16*)(ws + off); off += 524288;
  u16* fc2f  = (u16*)(ws + off); off += 524288;
  u16* P1    = (u16*)(ws + off); off += 33554432;  // LN-out -> cumsum -> smid (f16)
  u16* imv   = (u16*)(ws + off); off += 33554432;  // pre-scan imv (f16)
  u16* s16   = (u16*)(ws + off); off += 33554432;  // residual state s (f16)
  // bias(f32 512KB) + weightf(128KB) alias imv head: both dead before first k_qkv writes imv
  float* bias    = (float*)imv;
  u16*   weightf = (u16*)((char*)imv + 524288);

  k_bias<<<N_, M_, 0, stream>>>(bias);
  k_pack<<<64, 128, 0, stream>>>(weight, weightf, 256);
  k_pack_qkv<<<768, 128, 0, stream>>>(wqkv, wqkvf);
  k_pack<<<256, 128, 0, stream>>>(wo, wof, 256);      // 4 a-blocks of 256 rows
  k_pack<<<256, 128, 0, stream>>>(fc1_w, fc1f, 256);
  k_pack<<<256, 128, 0, stream>>>(fc2_w, fc2f, 1024); // C=256, K=1024
  k_init<<<R_/64, 512, 0, stream>>>(x, weightf, bias, ln_g, ln_b, s16, P1);
  for (int a=0; a<TK_; a++){
    k_qkv<<<R_/64, 512, 0, stream>>>(P1, wqkvf + a*196608, imv);
    k_scan<<<L_*2, 256, 0, stream>>>(imv, P1);
    k_wo<<<R_/64, 512, 0, stream>>>(P1, wof + a*65536, s16, lnz_g, lnz_b);
    if (a < TK_-1)
      k_fc<0><<<R_/64, 512, 0, stream>>>(P1, fc1f, fc1_b, fc2f, fc2_b, ln_g, ln_b, s16, out);
    else
      k_fc<1><<<R_/64, 512, 0, stream>>>(P1, fc1f, fc1_b, fc2f, fc2_b, ln_g, ln_b, s16, out);
  }
}

// Round 24
// 759.649 us; speedup vs baseline: 1.0450x; 1.0450x over previous
//
#include <hip/hip_runtime.h>

typedef unsigned int u32;
typedef unsigned short u16;
typedef _Float16 f16;
typedef __attribute__((ext_vector_type(8))) _Float16 f16x8;
typedef __attribute__((ext_vector_type(4))) float f32x4;
typedef __attribute__((ext_vector_type(4))) u16 u16x4;

#define L_ 128
#define N_ 512
#define M_ 256
#define TK_ 4
#define H_ 8
#define R_ (L_*N_)
#define FF_ 1024
// LDS frag-buffer strides (u16): MUST stay multiples of 8 u16 (16B) for b128 alignment
#define FS 1024
#define HS 512

__device__ __forceinline__ u16 f2h(float v){ f16 h=(f16)v; return __builtin_bit_cast(u16,h); }
__device__ __forceinline__ float h2f(u16 b){ return (float)__builtin_bit_cast(f16,b); }
__device__ __forceinline__ f32x4 mfmah(f16x8 a, f16x8 b, f32x4 c){
  return __builtin_amdgcn_mfma_f32_16x16x32_f16(a,b,c,0,0,0);
}
// sigmoid-form gelu: x * sigmoid(1.702x)
__device__ __forceinline__ float gelu_f(float x){
  float e = __expf(-1.702f*x);
  float r = __builtin_amdgcn_rcpf(e + 1.f);
  return x*r;
}

// Weight frag-major packing in GLOBAL (1024-stride, 512-half):
//   dst[(cg*(K/64)+k64)*1024 + st*512 + g*128 + lr*8 + e] = W[cg*16+lr][k64*64+st*32+g*8+e]

// ---------------- prep ----------------
__global__ void k_bias(float* __restrict__ bias){
  int j = blockIdx.x, l = threadIdx.x;
  int t = l>>1;
  float base = expf(-0.14391156831212757f * (float)t); // ln(10000)/64
  float ang = (float)j * base;
  bias[j*M_ + l] = (l&1) ? cosf(ang) : sinf(ang);
}

__global__ void k_pack(const float* __restrict__ src, u16* __restrict__ dst, int K){
  int b = blockIdx.x; int nk = K>>6; int cg = b/nk, k64 = b%nk;
  int t = threadIdx.x;
  int st = t>>6, g = (t>>4)&3, lr = t&15;
  const float* sp = src + (cg*16+lr)*K + k64*64 + st*32 + g*8;
  f16x8 hv;
  #pragma unroll
  for (int e=0;e<8;e++) hv[e] = (f16)sp[e];
  *(f16x8*)(dst + b*1024 + t*8) = hv;
}

__global__ void k_pack_qkv(const float* __restrict__ w, u16* __restrict__ dst){
  int b = blockIdx.x;              // a*192 + grp*4 + k64
  int a = b/192; int rmn = b%192; int grp = rmn>>2, k64 = rmn&3;
  int hd = grp/6, cidx = grp%6;
  int t = threadIdx.x;
  int st = t>>6, g = (t>>4)&3, lr = t&15;
  int cl = cidx*16 + lr;           // 0..95
  int x = cl>>5, d = cl&31;
  const float* sp = w + (((a*3+x)*H_+hd)*32 + d)*M_ + k64*64 + st*32 + g*8;
  f16x8 hv;
  #pragma unroll
  for (int e=0;e<8;e++) hv[e] = (f16)sp[e];
  *(f16x8*)(dst + b*1024 + t*8) = hv;
}

// A-staging (f16 src): 64 rows -> frag LDS. Coalesced 64B/thread.
__device__ __forceinline__ void stageA16(const u16* __restrict__ src, u16* __restrict__ Abuf,
                                         int rowbase, int tid){
  int row = tid>>3, skh = tid&7;
  int k64 = skh>>1, st = skh&1;
  int rg = row>>4, lr = row&15;
  const u16* sp = src + (rowbase+row)*M_ + k64*64 + st*32;
  u16* dp = Abuf + (k64*4+rg)*FS + st*HS + lr*8;
  #pragma unroll
  for (int gg=0;gg<4;gg++)
    *(uint4*)(dp + gg*128) = *(const uint4*)(sp + gg*8);
}

// ---------------- k_init: z = x @ weight^T + bias; s16=f16(z), P1=f16(LN(z)) ----------------
__global__ __launch_bounds__(512) void k_init(const float* __restrict__ X, const u16* __restrict__ Wf,
    const float* __restrict__ bias, const float* __restrict__ lg, const float* __restrict__ lb,
    u16* __restrict__ s16, u16* __restrict__ P1){
  __shared__ __align__(16) u16 Abuf[16*FS];
  __shared__ float zs[8][64][2];
  int tid = threadIdx.x;
  int wx = tid>>6, lane = tid&63;
  int g = lane>>4, lr = lane&15;
  int lo = g*128 + lr*8;
  int rowbase = blockIdx.x*64;
  { // stage A (f32 -> f16 frag-pack)
    int row = tid>>3, skh = tid&7;
    int k64 = skh>>1, st = skh&1;
    int rg = row>>4, slr = row&15;
    const float* sp = X + (rowbase+row)*M_ + k64*64 + st*32;
    u16* dp = Abuf + (k64*4+rg)*FS + st*HS + slr*8;
    #pragma unroll
    for (int gg=0;gg<4;gg++){
      f16x8 hv;
      #pragma unroll
      for (int e=0;e<8;e++) hv[e] = (f16)sp[gg*8+e];
      *(f16x8*)(dp + gg*128) = hv;
    }
  }
  __syncthreads();
  f32x4 acc[4][2];
  #pragma unroll
  for (int i=0;i<4;i++){ acc[i][0]=0.f; acc[i][1]=0.f; }
  #pragma unroll
  for (int k64=0;k64<4;k64++)
    #pragma unroll
    for (int st=0;st<2;st++){
      f16x8 a[4], b[2];
      #pragma unroll
      for (int i=0;i<4;i++) a[i] = *(const f16x8*)(Abuf + (k64*4 + i)*FS + st*HS + lo);
      #pragma unroll
      for (int j=0;j<2;j++) b[j] = *(const f16x8*)(Wf + ((wx*2+j)*4 + k64)*1024 + st*512 + lo);
      #pragma unroll
      for (int i=0;i<4;i++)
        #pragma unroll
        for (int j=0;j<2;j++) acc[i][j] = mfmah(a[i], b[j], acc[i][j]);
    }
  // epilogue: +bias -> s16; LN -> P1
  #pragma unroll
  for (int i=0;i<4;i++)
    #pragma unroll
    for (int j=0;j<2;j++)
      #pragma unroll
      for (int r=0;r<4;r++){
        int row = rowbase + i*16 + g*4 + r;
        int col = wx*32 + j*16 + lr;
        acc[i][j][r] += bias[(row & (N_-1))*M_ + col];
        s16[row*M_ + col] = f2h(acc[i][j][r]);
      }
  #pragma unroll
  for (int i=0;i<4;i++)
    #pragma unroll
    for (int r=0;r<4;r++){
      float ps = 0.f, qs = 0.f;
      #pragma unroll
      for (int j=0;j<2;j++){ float t = acc[i][j][r]; ps += t; qs += t*t; }
      ps += __shfl_xor(ps,1); qs += __shfl_xor(qs,1);
      ps += __shfl_xor(ps,2); qs += __shfl_xor(qs,2);
      ps += __shfl_xor(ps,4); qs += __shfl_xor(qs,4);
      ps += __shfl_xor(ps,8); qs += __shfl_xor(qs,8);
      if (lr == 0){
        int rowl = i*16 + g*4 + r;
        zs[wx][rowl][0] = ps;
        zs[wx][rowl][1] = qs;
      }
    }
  __syncthreads();
  #pragma unroll
  for (int i=0;i<4;i++)
    #pragma unroll
    for (int r=0;r<4;r++){
      int rowl = i*16 + g*4 + r;
      float sum=0.f, sq=0.f;
      #pragma unroll
      for (int q=0;q<8;q++){ sum += zs[q][rowl][0]; sq += zs[q][rowl][1]; }
      float mean = sum*(1.f/M_);
      float var  = sq*(1.f/M_) - mean*mean;
      float rstd = rsqrtf(var + 1e-5f);
      int row = rowbase + rowl;
      #pragma unroll
      for (int j=0;j<2;j++){
        int col = wx*32 + j*16 + lr;
        P1[row*M_ + col] = f2h((acc[i][j][r]-mean)*rstd*lg[col] + lb[col]);
      }
    }
}

// ---------------- QKV GEMM + fused rsa -> imv(f16), 2-pass (QK then V) ----------------
__global__ __launch_bounds__(512) void k_qkv(const u16* __restrict__ P1, const u16* __restrict__ Wq,
    u16* __restrict__ imv){
  __shared__ __align__(16) u16 Abuf[16*FS];
  int tid = threadIdx.x;
  int hd = tid>>6, lane = tid&63;
  int g = lane>>4, lr = lane&15;
  int lo = g*128 + lr*8;
  int rowbase = blockIdx.x*64;
  stageA16(P1, Abuf, rowbase, tid);
  __syncthreads();
  const u16* Wb = Wq + hd*6*4096;
  const float isd = 0.17677669529663687f; // 1/sqrt(32)
  // ---- pass 1: q,k (c=0..3) ----
  float rsa[4][4];
  {
    f32x4 aqk[4][4];
    #pragma unroll
    for (int i=0;i<4;i++)
      #pragma unroll
      for (int c=0;c<4;c++) aqk[i][c] = 0.f;
    #pragma unroll
    for (int k64=0;k64<4;k64++)
      #pragma unroll
      for (int st=0;st<2;st++){
        f16x8 a[4];
        #pragma unroll
        for (int i=0;i<4;i++) a[i] = *(const f16x8*)(Abuf + (k64*4 + i)*FS + st*HS + lo);
        #pragma unroll
        for (int c=0;c<4;c++){
          f16x8 b = *(const f16x8*)(Wb + (c*4 + k64)*1024 + st*512 + lo);
          #pragma unroll
          for (int i=0;i<4;i++) aqk[i][c] = mfmah(a[i], b, aqk[i][c]);
        }
      }
    #pragma unroll
    for (int i=0;i<4;i++){
      f32x4 p = aqk[i][0]*aqk[i][2] + aqk[i][1]*aqk[i][3];
      #pragma unroll
      for (int r=0;r<4;r++){
        float v = p[r];
        v += __shfl_xor(v,1); v += __shfl_xor(v,2);
        v += __shfl_xor(v,4); v += __shfl_xor(v,8);
        rsa[i][r] = v * isd;
      }
    }
  }
  // ---- pass 2: v (c=4,5) ----
  f32x4 av[4][2];
  #pragma unroll
  for (int i=0;i<4;i++){ av[i][0]=0.f; av[i][1]=0.f; }
  #pragma unroll
  for (int k64=0;k64<4;k64++)
    #pragma unroll
    for (int st=0;st<2;st++){
      f16x8 a[4];
      #pragma unroll
      for (int i=0;i<4;i++) a[i] = *(const f16x8*)(Abuf + (k64*4 + i)*FS + st*HS + lo);
      #pragma unroll
      for (int c=0;c<2;c++){
        f16x8 b = *(const f16x8*)(Wb + ((4+c)*4 + k64)*1024 + st*512 + lo);
        #pragma unroll
        for (int i=0;i<4;i++) av[i][c] = mfmah(a[i], b, av[i][c]);
      }
    }
  #pragma unroll
  for (int i=0;i<4;i++)
    #pragma unroll
    for (int r=0;r<4;r++){
      int row = rowbase + i*16 + g*4 + r;
      imv[row*M_ + hd*32 + lr]      = f2h(rsa[i][r]*av[i][0][r]);
      imv[row*M_ + hd*32 + 16 + lr] = f2h(rsa[i][r]*av[i][1][r]);
    }
}

// ---------------- cumsum over j: u32-pair vectorized; grid (L_*2), block (64 mpair x 4 jc) ----------------
__global__ __launch_bounds__(256) void k_scan(const u16* __restrict__ imv, u16* __restrict__ P1){
  __shared__ float tot[4][64][2];
  const u32* s32 = (const u32*)imv;
  u32* d32 = (u32*)P1;
  int bi = blockIdx.x;
  int i = bi>>1, mc = bi&1;
  int tid = threadIdx.x;
  int ml = tid&63, jc = tid>>6;
  int base = i*(N_*M_/2) + jc*128*(M_/2) + mc*64 + ml;   // u32 units
  float a0 = 0.f, a1 = 0.f;
  for (int jb=0;jb<128;jb+=8){
    u32 t[8];
    #pragma unroll
    for (int u=0;u<8;u++) t[u] = s32[base + (jb+u)*(M_/2)];
    #pragma unroll
    for (int u=0;u<8;u++){ a0 += h2f((u16)(t[u]&0xffff)); a1 += h2f((u16)(t[u]>>16)); }
  }
  tot[jc][ml][0] = a0; tot[jc][ml][1] = a1;
  __syncthreads();
  float p0 = 0.f, p1 = 0.f;
  #pragma unroll
  for (int q=0;q<3;q++) if (q<jc){ p0 += tot[q][ml][0]; p1 += tot[q][ml][1]; }
  a0 = p0; a1 = p1;
  for (int jb=0;jb<128;jb+=8){
    u32 t[8];
    #pragma unroll
    for (int u=0;u<8;u++) t[u] = s32[base + (jb+u)*(M_/2)];
    #pragma unroll
    for (int u=0;u<8;u++){
      a0 += h2f((u16)(t[u]&0xffff));
      a1 += h2f((u16)(t[u]>>16));
      d32[base + (jb+u)*(M_/2)] = (u32)f2h(a0) | ((u32)f2h(a1)<<16);
    }
  }
}

// ---------------- Wo GEMM + s_old(f16) + LN + residual -> P1(f16, in-place) ----------------
__global__ __launch_bounds__(512) void k_wo(u16* __restrict__ P1, const u16* __restrict__ Wf,
    const u16* __restrict__ s16, const float* __restrict__ lg, const float* __restrict__ lb){
  __shared__ __align__(16) u16 Abuf[16*FS];
  __shared__ float zs[8][64][2];
  int tid = threadIdx.x;
  int wx = tid>>6, lane = tid&63;
  int g = lane>>4, lr = lane&15;
  int lo = g*128 + lr*8;
  int rowbase = blockIdx.x*64;
  stageA16(P1, Abuf, rowbase, tid);
  __syncthreads();
  f32x4 acc[4][2];
  #pragma unroll
  for (int i=0;i<4;i++){ acc[i][0]=0.f; acc[i][1]=0.f; }
  #pragma unroll
  for (int k64=0;k64<4;k64++)
    #pragma unroll
    for (int st=0;st<2;st++){
      f16x8 a[4], b[2];
      #pragma unroll
      for (int i=0;i<4;i++) a[i] = *(const f16x8*)(Abuf + (k64*4 + i)*FS + st*HS + lo);
      #pragma unroll
      for (int j=0;j<2;j++) b[j] = *(const f16x8*)(Wf + ((wx*2+j)*4 + k64)*1024 + st*512 + lo);
      #pragma unroll
      for (int i=0;i<4;i++)
        #pragma unroll
        for (int j=0;j<2;j++) acc[i][j] = mfmah(a[i], b[j], acc[i][j]);
    }
  #pragma unroll
  for (int i=0;i<4;i++)
    #pragma unroll
    for (int j=0;j<2;j++)
      #pragma unroll
      for (int r=0;r<4;r++){
        int row = rowbase + i*16 + g*4 + r;
        int col = wx*32 + j*16 + lr;
        acc[i][j][r] += h2f(s16[row*M_ + col]);
      }
  #pragma unroll
  for (int i=0;i<4;i++)
    #pragma unroll
    for (int r=0;r<4;r++){
      float ps = 0.f, qs = 0.f;
      #pragma unroll
      for (int j=0;j<2;j++){ float t = acc[i][j][r]; ps += t; qs += t*t; }
      ps += __shfl_xor(ps,1); qs += __shfl_xor(qs,1);
      ps += __shfl_xor(ps,2); qs += __shfl_xor(qs,2);
      ps += __shfl_xor(ps,4); qs += __shfl_xor(qs,4);
      ps += __shfl_xor(ps,8); qs += __shfl_xor(qs,8);
      if (lr == 0){
        int rowl = i*16 + g*4 + r;
        zs[wx][rowl][0] = ps;
        zs[wx][rowl][1] = qs;
      }
    }
  __syncthreads();
  #pragma unroll
  for (int i=0;i<4;i++)
    #pragma unroll
    for (int r=0;r<4;r++){
      int rowl = i*16 + g*4 + r;
      float sum=0.f, sq=0.f;
      #pragma unroll
      for (int q=0;q<8;q++){ sum += zs[q][rowl][0]; sq += zs[q][rowl][1]; }
      float mean = sum*(1.f/M_);
      float var  = sq*(1.f/M_) - mean*mean;
      float rstd = rsqrtf(var + 1e-5f);
      int row = rowbase + rowl;
      #pragma unroll
      for (int j=0;j<2;j++){
        int col = wx*32 + j*16 + lr;
        float zv = acc[i][j][r];
        P1[row*M_ + col] = f2h((zv-mean)*rstd*lg[col] + lb[col] + zv);
      }
    }
}

// ---------------- fused MLP + LN (best config: H-dbuf, 1 barrier/chunk) ----------------
// LAST=0: z -> s16(f16), LN(z) -> P1.  LAST=1: z -> out(f32) only.
template<int LAST>
__global__ __launch_bounds__(512) void k_fc(u16* __restrict__ P1,
    const u16* __restrict__ W1f, const float* __restrict__ b1,
    const u16* __restrict__ W2f, const float* __restrict__ b2,
    const float* __restrict__ lg, const float* __restrict__ lb,
    u16* __restrict__ s16, float* __restrict__ out){
  __shared__ __align__(16) u16 Abuf[16*FS];
  __shared__ __align__(16) u16 Hbuf[2][64*128];  // 32KB
  __shared__ float zs[8][64][2];                 // 4KB
  int tid = threadIdx.x;
  int wx = tid>>6, lane = tid&63;
  int g = lane>>4, lr = lane&15;
  int lo = g*128 + lr*8;
  int rowbase = blockIdx.x*64;
  stageA16(P1, Abuf, rowbase, tid);
  __syncthreads();
  f32x4 acc2[4][2];
  #pragma unroll
  for (int i=0;i<4;i++){ acc2[i][0]=0.f; acc2[i][1]=0.f; }
  for (int c=0;c<8;c++){
    u16* Hb = Hbuf[c&1];
    // ---- FC1^T: this wave's 16 fcols = c*128 + wx*16; K=256 ----
    f32x4 acc1[4];
    #pragma unroll
    for (int j=0;j<4;j++) acc1[j] = 0.f;
    #pragma unroll
    for (int k64=0;k64<4;k64++)
      #pragma unroll
      for (int st=0;st<2;st++){
        f16x8 aw = *(const f16x8*)(W1f + ((c*8 + wx)*4 + k64)*1024 + st*512 + lo);
        #pragma unroll
        for (int j=0;j<4;j++){
          f16x8 bs = *(const f16x8*)(Abuf + (k64*4 + j)*FS + st*HS + lo);
          acc1[j] = mfmah(aw, bs, acc1[j]);
        }
      }
    // ---- gelu -> Hb (A-frag layout, XOR-swizzled) ----
    {
      int fl = wx*16 + g*4;            // fcol local 0..127 (+r)
      int kc = fl>>6, kloc = fl&63;
      float4 b1v = *(const float4*)(b1 + c*128 + fl);
      float bb[4] = {b1v.x, b1v.y, b1v.z, b1v.w};
      #pragma unroll
      for (int j=0;j<4;j++){
        int row = j*16 + lr;
        u16x4 hv;
        #pragma unroll
        for (int r=0;r<4;r++)
          hv[r] = f2h(gelu_f(acc1[j][r] + bb[r]));
        int phys = ((kloc>>3) ^ row) & 7;
        *(u16x4*)(Hb + row*128 + kc*64 + phys*8 + (kloc&7)) = hv;
      }
    }
    __syncthreads();   // only barrier per chunk: H(c) visible; prev readers used other buffer
    // ---- FC2 partial: k in [c*128,+128); out cols wx*32..+32 ----
    #pragma unroll
    for (int kcl=0;kcl<2;kcl++)
      #pragma unroll
      for (int st=0;st<2;st++){
        f16x8 ah[4], bb2[2];
        #pragma unroll
        for (int j=0;j<2;j++)
          bb2[j] = *(const f16x8*)(W2f + ((wx*2+j)*16 + c*2 + kcl)*1024 + st*512 + lo);
        #pragma unroll
        for (int i=0;i<4;i++){
          int hrow = i*16 + lr;
          int phys = (((st<<2)|g) ^ hrow) & 7;
          ah[i] = *(const f16x8*)(Hb + hrow*128 + kcl*64 + phys*8);
        }
        #pragma unroll
        for (int i=0;i<4;i++)
          #pragma unroll
          for (int j=0;j<2;j++) acc2[i][j] = mfmah(ah[i], bb2[j], acc2[i][j]);
      }
  }
  // ---- epilogue ----
  #pragma unroll
  for (int i=0;i<4;i++)
    #pragma unroll
    for (int j=0;j<2;j++)
      #pragma unroll
      for (int r=0;r<4;r++){
        int row = rowbase + i*16 + g*4 + r;
        int col = wx*32 + j*16 + lr;
        acc2[i][j][r] += b2[col];
        if (LAST) out[row*M_ + col] = acc2[i][j][r];
        else      s16[row*M_ + col] = f2h(acc2[i][j][r]);
      }
  if (!LAST){
    #pragma unroll
    for (int i=0;i<4;i++)
      #pragma unroll
      for (int r=0;r<4;r++){
        float ps = 0.f, qs = 0.f;
        #pragma unroll
        for (int j=0;j<2;j++){ float t = acc2[i][j][r]; ps += t; qs += t*t; }
        ps += __shfl_xor(ps,1); qs += __shfl_xor(qs,1);
        ps += __shfl_xor(ps,2); qs += __shfl_xor(qs,2);
        ps += __shfl_xor(ps,4); qs += __shfl_xor(qs,4);
        ps += __shfl_xor(ps,8); qs += __shfl_xor(qs,8);
        if (lr == 0){
          int rowl = i*16 + g*4 + r;
          zs[wx][rowl][0] = ps;
          zs[wx][rowl][1] = qs;
        }
      }
    __syncthreads();
    #pragma unroll
    for (int i=0;i<4;i++)
      #pragma unroll
      for (int r=0;r<4;r++){
        int rowl = i*16 + g*4 + r;
        float sum=0.f, sq=0.f;
        #pragma unroll
        for (int q=0;q<8;q++){ sum += zs[q][rowl][0]; sq += zs[q][rowl][1]; }
        float mean = sum*(1.f/M_);
        float var  = sq*(1.f/M_) - mean*mean;
        float rstd = rsqrtf(var + 1e-5f);
        int row = rowbase + rowl;
        #pragma unroll
        for (int j=0;j<2;j++){
          int col = wx*32 + j*16 + lr;
          P1[row*M_ + col] = f2h((acc2[i][j][r]-mean)*rstd*lg[col] + lb[col]);
        }
      }
  }
}

extern "C" void kernel_launch(void* const* d_in, const int* in_sizes, int n_in,
                              void* d_out, int out_size, void* d_ws, size_t ws_size,
                              hipStream_t stream){
  const float* x      = (const float*)d_in[0];
  const float* weight = (const float*)d_in[1];
  const float* wqkv   = (const float*)d_in[2];
  const float* wo     = (const float*)d_in[3];
  const float* ln_g   = (const float*)d_in[4];
  const float* ln_b   = (const float*)d_in[5];
  const float* lnz_g  = (const float*)d_in[6];
  const float* lnz_b  = (const float*)d_in[7];
  const float* fc1_w  = (const float*)d_in[8];
  const float* fc1_b  = (const float*)d_in[9];
  const float* fc2_w  = (const float*)d_in[10];
  const float* fc2_b  = (const float*)d_in[11];
  float* out = (float*)d_out;
  char* ws = (char*)d_ws;
  size_t off = 0;
  u16* wqkvf = (u16*)(ws + off); off += 1572864;   // 4*192 frags
  u16* wof   = (u16*)(ws + off); off += 524288;
  u16* fc1f  = (u16*)(ws + off); off += 524288;
  u16* fc2f  = (u16*)(ws + off); off += 524288;
  u16* P1    = (u16*)(ws + off); off += 33554432;  // LN-out -> cumsum -> smid (f16)
  u16* imv   = (u16*)(ws + off); off += 33554432;  // pre-scan imv (f16)
  u16* s16   = (u16*)(ws + off); off += 33554432;  // residual state s (f16)
  // bias(f32 512KB) + weightf(128KB) alias imv head: both dead before first k_qkv writes imv
  float* bias    = (float*)imv;
  u16*   weightf = (u16*)((char*)imv + 524288);

  k_bias<<<N_, M_, 0, stream>>>(bias);
  k_pack<<<64, 128, 0, stream>>>(weight, weightf, 256);
  k_pack_qkv<<<768, 128, 0, stream>>>(wqkv, wqkvf);
  k_pack<<<256, 128, 0, stream>>>(wo, wof, 256);      // 4 a-blocks of 256 rows
  k_pack<<<256, 128, 0, stream>>>(fc1_w, fc1f, 256);
  k_pack<<<256, 128, 0, stream>>>(fc2_w, fc2f, 1024); // C=256, K=1024
  k_init<<<R_/64, 512, 0, stream>>>(x, weightf, bias, ln_g, ln_b, s16, P1);
  for (int a=0; a<TK_; a++){
    k_qkv<<<R_/64, 512, 0, stream>>>(P1, wqkvf + a*196608, imv);
    k_scan<<<L_*2, 256, 0, stream>>>(imv, P1);
    k_wo<<<R_/64, 512, 0, stream>>>(P1, wof + a*65536, s16, lnz_g, lnz_b);
    if (a < TK_-1)
      k_fc<0><<<R_/64, 512, 0, stream>>>(P1, fc1f, fc1_b, fc2f, fc2_b, ln_g, ln_b, s16, out);
    else
      k_fc<1><<<R_/64, 512, 0, stream>>>(P1, fc1f, fc1_b, fc2f, fc2_b, ln_g, ln_b, s16, out);
  }
}